// Round 1
// baseline (337.624 us; speedup 1.0000x reference)
//
#include <hip/hip_runtime.h>

// ---------------------------------------------------------------------------
// QuantizedLinear: y = x @ ((q - zp)*s)^T + bias
// Decomposition: y[m,o] = s[o]*G[m,o] - s[o]*zp[o]*rowsum[m] + bias[o]
//   G = x_bf16 @ q_bf16^T   (bf16 MFMA; q<=254 is EXACT in bf16)
//   rowsum[m] = sum_k bf16(x[m,k])  (f32 accumulation)
// M=8192, K=4096, N=4096.
// ---------------------------------------------------------------------------

typedef unsigned short u16;
typedef __attribute__((ext_vector_type(8))) short bf16x8;
typedef __attribute__((ext_vector_type(8))) u16 u16x8;
typedef __attribute__((ext_vector_type(4))) float f32x4;

#define M_TOK 8192
#define KDIM 4096
#define NDIM 4096

// --- helpers ---------------------------------------------------------------

__device__ __forceinline__ u16 f32_to_bf16_rne(float f) {
  unsigned u = __float_as_uint(f);
  unsigned r = u + 0x7FFFu + ((u >> 16) & 1u);
  return (u16)(r >> 16);
}

// exact for integers 0..255 (fits in 8-bit significand)
__device__ __forceinline__ u16 i32_to_bf16(int v) {
  return (u16)(__float_as_uint((float)v) >> 16);
}

#define GLDS(gptr, lptr)                                                      \
  __builtin_amdgcn_global_load_lds(                                          \
      (const __attribute__((address_space(1))) void*)(gptr),                 \
      (__attribute__((address_space(3))) void*)(lptr), 16, 0, 0)

// --- kernel 1: x f32 -> bf16, fused row-sum (of the ROUNDED values) --------

__global__ __launch_bounds__(256) void convert_x_kernel(
    const float* __restrict__ x, u16* __restrict__ xb,
    float* __restrict__ rowsum) {
  const int row = blockIdx.x;  // one block per row of 4096
  const int tid = threadIdx.x;
  const float* xr = x + (size_t)row * KDIM;
  u16* xbr = xb + (size_t)row * KDIM;
  float acc = 0.f;
#pragma unroll
  for (int i = 0; i < 2; ++i) {
    const int e = (i * 256 + tid) * 8;
    const float4 a = *(const float4*)(xr + e);
    const float4 b = *(const float4*)(xr + e + 4);
    float v[8] = {a.x, a.y, a.z, a.w, b.x, b.y, b.z, b.w};
    u16x8 o;
#pragma unroll
    for (int j = 0; j < 8; ++j) {
      const u16 h = f32_to_bf16_rne(v[j]);
      o[j] = (u16)h;
      acc += __uint_as_float((unsigned)h << 16);  // sum of rounded values
    }
    *(u16x8*)(xbr + e) = o;
  }
  // wave reduce (64-wide), then cross-wave via LDS
#pragma unroll
  for (int off = 32; off > 0; off >>= 1) acc += __shfl_down(acc, off, 64);
  __shared__ float red[4];
  if ((tid & 63) == 0) red[tid >> 6] = acc;
  __syncthreads();
  if (tid == 0) rowsum[row] = red[0] + red[1] + red[2] + red[3];
}

// --- kernel 2: w int32 -> bf16 (exact) --------------------------------------

__global__ __launch_bounds__(256) void convert_w_kernel(
    const int* __restrict__ wq, u16* __restrict__ wb) {
  const size_t idx = (size_t)blockIdx.x * 256 + threadIdx.x;  // 8 elems each
  const int4* src = (const int4*)wq + idx * 2;
  const int4 a = src[0];
  const int4 b = src[1];
  u16x8 o;
  o[0] = i32_to_bf16(a.x);
  o[1] = i32_to_bf16(a.y);
  o[2] = i32_to_bf16(a.z);
  o[3] = i32_to_bf16(a.w);
  o[4] = i32_to_bf16(b.x);
  o[5] = i32_to_bf16(b.y);
  o[6] = i32_to_bf16(b.z);
  o[7] = i32_to_bf16(b.w);
  *((u16x8*)wb + idx) = o;
}

// --- kernel 3: bf16 GEMM (B^T layout), fused dequant epilogue ---------------
// m97 structure: 128x128 tile, BK=64, 4 waves (2x2), 4x4 frags of 16x16x32,
// global_load_lds width=16, single-buffered 2-barrier K-loop.

__global__ __launch_bounds__(256, 3) void qlin_gemm_kernel(
    const u16* __restrict__ A,        // [M][K] bf16 bits
    const u16* __restrict__ B,        // [N][K] bf16 bits
    const float* __restrict__ rowsum, // [M]
    const float* __restrict__ scale,  // [N]
    const float* __restrict__ zp,     // [N]
    const float* __restrict__ bias,   // [N]
    float* __restrict__ out) {        // [M][N]
  __shared__ __align__(16) u16 Al[128 * 64];
  __shared__ __align__(16) u16 Bl[128 * 64];

  const int tid = threadIdx.x;
  const int wave = tid >> 6;
  const int lane = tid & 63;
  const int bn = blockIdx.x;  // 0..31
  const int bm = blockIdx.y;  // 0..63
  const int row0 = bm * 128;
  const int col0 = bn * 128;
  const int wm = wave >> 1;   // 0..1
  const int wn = wave & 1;    // 0..1

  f32x4 acc[4][4] = {};

  // staging: thread t loads 8 contiguous bf16 at tile row (t>>3), col (t&7)*8;
  // issue i advances 32 rows. LDS dest is linear: wave-uniform base + lane*16.
  const u16* Ag0 = A + (size_t)(row0 + (tid >> 3)) * KDIM + (tid & 7) * 8;
  const u16* Bg0 = B + (size_t)(col0 + (tid >> 3)) * KDIM + (tid & 7) * 8;
  char* AlBase = (char*)Al + wave * 1024;
  char* BlBase = (char*)Bl + wave * 1024;

  // fragment read addrs: lane l reads row (l&15), k = (l>>4)*8 (8 contiguous)
  const int fr = lane & 15;
  const int fk = (lane >> 4) * 8;
  const u16* Alp = Al + (wm * 64 + fr) * 64 + fk;
  const u16* Blp = Bl + (wn * 64 + fr) * 64 + fk;

  for (int kt = 0; kt < KDIM / 64; ++kt) {
    __syncthreads();  // previous iter's LDS reads done before overwrite
    const u16* Ag = Ag0 + kt * 64;
    const u16* Bg = Bg0 + kt * 64;
#pragma unroll
    for (int i = 0; i < 4; ++i) {
      GLDS(Ag + (size_t)i * 32 * KDIM, AlBase + i * 4096);
      GLDS(Bg + (size_t)i * 32 * KDIM, BlBase + i * 4096);
    }
    __syncthreads();  // compiler drains vmcnt(0) before s_barrier

#pragma unroll
    for (int ks = 0; ks < 2; ++ks) {
      bf16x8 af[4], bf[4];
#pragma unroll
      for (int m = 0; m < 4; ++m)
        af[m] = *(const bf16x8*)(Alp + m * 16 * 64 + ks * 32);
#pragma unroll
      for (int n = 0; n < 4; ++n)
        bf[n] = *(const bf16x8*)(Blp + n * 16 * 64 + ks * 32);
#pragma unroll
      for (int m = 0; m < 4; ++m)
#pragma unroll
        for (int n = 0; n < 4; ++n)
          acc[m][n] = __builtin_amdgcn_mfma_f32_16x16x32_bf16(
              af[m], bf[n], acc[m][n], 0, 0, 0);
    }
  }

  // epilogue: C/D layout col=lane&15, row=(lane>>4)*4+reg (m89-verified)
  const int r0 = row0 + wm * 64 + (lane >> 4) * 4;
  const int c0 = col0 + wn * 64 + (lane & 15);
#pragma unroll
  for (int n = 0; n < 4; ++n) {
    const int col = c0 + n * 16;
    const float s = scale[col];
    const float szp = s * zp[col];
    const float bz = bias[col];
#pragma unroll
    for (int m = 0; m < 4; ++m) {
      const int row = r0 + m * 16;
#pragma unroll
      for (int r = 0; r < 4; ++r) {
        out[(size_t)(row + r) * NDIM + col] =
            s * acc[m][n][r] - szp * rowsum[row + r] + bz;
      }
    }
  }
}

// --- launch ------------------------------------------------------------------

extern "C" void kernel_launch(void* const* d_in, const int* in_sizes, int n_in,
                              void* d_out, int out_size, void* d_ws,
                              size_t ws_size, hipStream_t stream) {
  const float* x = (const float*)d_in[0];      // [8192,4096] f32
  const int* wq = (const int*)d_in[1];         // [4096,4096] i32
  const float* scale = (const float*)d_in[2];  // [4096]
  const float* zp = (const float*)d_in[3];     // [4096]
  const float* bias = (const float*)d_in[4];   // [4096]
  float* out = (float*)d_out;                  // [8192,4096] f32

  // workspace layout (96.03 MiB): xb | wb | rowsum — fully rewritten each call
  char* ws = (char*)d_ws;
  u16* xb = (u16*)ws;                                      // 64 MiB
  u16* wb = (u16*)(ws + (size_t)M_TOK * KDIM * 2);         // 32 MiB
  float* rowsum = (float*)(ws + (size_t)M_TOK * KDIM * 2 +
                           (size_t)NDIM * KDIM * 2);       // 32 KiB

  convert_x_kernel<<<M_TOK, 256, 0, stream>>>(x, xb, rowsum);
  convert_w_kernel<<<(NDIM * (size_t)KDIM) / (256 * 8), 256, 0, stream>>>(wq, wb);

  dim3 grid(NDIM / 128, M_TOK / 128);  // (32, 64)
  qlin_gemm_kernel<<<grid, 256, 0, stream>>>(xb, wb, rowsum, scale, zp, bias,
                                             out);
}

// Round 3
// 291.298 us; speedup vs baseline: 1.1590x; 1.1590x over previous
//
#include <hip/hip_runtime.h>

// ---------------------------------------------------------------------------
// QuantizedLinear: y = x @ ((q - zp)*s)^T + bias
// Decomposition: y[m,o] = s[o]*G[m,o] - s[o]*zp[o]*rowsum[m] + bias[o]
//   G = x_bf16 @ q_bf16^T   (bf16 MFMA; q in [0,255) is EXACT in bf16)
// GEMM: 256x256 8-phase template (m201): BK=64, 8 waves (2Mx4N), 128 KiB
// dbuf LDS, counted vmcnt (4 steady / 0 tail drain), T2 st-swizzle
// (pre-swizzled global source + swizzled ds_read), T5 setprio, T1 XCD swizzle.
// ---------------------------------------------------------------------------

typedef unsigned short u16;
typedef __attribute__((ext_vector_type(8))) short bf16x8;
typedef __attribute__((ext_vector_type(8))) u16 u16x8;
typedef __attribute__((ext_vector_type(4))) float f32x4;

#define M_TOK 8192
#define KDIM 4096
#define NDIM 4096
#define NT (KDIM / 64)  // 64 K-tiles

// --- helpers ---------------------------------------------------------------

__device__ __forceinline__ u16 f32_to_bf16_rne(float f) {
  unsigned u = __float_as_uint(f);
  unsigned r = u + 0x7FFFu + ((u >> 16) & 1u);
  return (u16)(r >> 16);
}

__device__ __forceinline__ u16 i32_to_bf16(int v) {
  return (u16)(__float_as_uint((float)v) >> 16);  // exact for 0..255
}

#define GLDS(gptr, lptr)                                                      \
  __builtin_amdgcn_global_load_lds(                                          \
      (const __attribute__((address_space(1))) void*)(gptr),                 \
      (__attribute__((address_space(3))) void*)(lptr), 16, 0, 0)

// --- kernel 1: x f32 -> bf16, fused row-sum (of the ROUNDED values) --------

__global__ __launch_bounds__(256) void convert_x_kernel(
    const float* __restrict__ x, u16* __restrict__ xb,
    float* __restrict__ rowsum) {
  const int row = blockIdx.x;
  const int tid = threadIdx.x;
  const float* xr = x + (size_t)row * KDIM;
  u16* xbr = xb + (size_t)row * KDIM;
  float acc = 0.f;
#pragma unroll
  for (int i = 0; i < 2; ++i) {
    const int e = (i * 256 + tid) * 8;
    const float4 a = *(const float4*)(xr + e);
    const float4 b = *(const float4*)(xr + e + 4);
    float v[8] = {a.x, a.y, a.z, a.w, b.x, b.y, b.z, b.w};
    u16x8 o;
#pragma unroll
    for (int j = 0; j < 8; ++j) {
      const u16 h = f32_to_bf16_rne(v[j]);
      o[j] = (u16)h;
      acc += __uint_as_float((unsigned)h << 16);
    }
    *(u16x8*)(xbr + e) = o;
  }
#pragma unroll
  for (int off = 32; off > 0; off >>= 1) acc += __shfl_down(acc, off, 64);
  __shared__ float red[4];
  if ((tid & 63) == 0) red[tid >> 6] = acc;
  __syncthreads();
  if (tid == 0) rowsum[row] = red[0] + red[1] + red[2] + red[3];
}

// --- kernel 2: w int32 -> bf16 (exact) --------------------------------------

__global__ __launch_bounds__(256) void convert_w_kernel(
    const int* __restrict__ wq, u16* __restrict__ wb) {
  const size_t idx = (size_t)blockIdx.x * 256 + threadIdx.x;
  const int4* src = (const int4*)wq + idx * 2;
  const int4 a = src[0];
  const int4 b = src[1];
  u16x8 o;
  o[0] = i32_to_bf16(a.x); o[1] = i32_to_bf16(a.y);
  o[2] = i32_to_bf16(a.z); o[3] = i32_to_bf16(a.w);
  o[4] = i32_to_bf16(b.x); o[5] = i32_to_bf16(b.y);
  o[6] = i32_to_bf16(b.z); o[7] = i32_to_bf16(b.w);
  *((u16x8*)wb + idx) = o;
}

// --- kernel 3: 256x256 8-phase bf16 GEMM, fused dequant epilogue ------------
// LDS: Al[2][256][64], Bl[2][256][64] bf16 = 128 KiB (dynamic).
// Half-tile = 128 rows x 64 k = 2 global_load_lds per thread.
// Stage schedule (tile t): p0:B(t+1)h0  p1:B(t+1)h1  p2:A(t+2)h0  p3:A(t+2)h1
// Tile-end wait ledger (per wave):
//   steady (t < NT-2): 12 outstanding -> vmcnt(4): A(t+1),B(t+1) landed,
//                      A(t+2)'s 4 stay in flight.
//   t == NT-2: A(NT) skipped, only 8 outstanding -> vmcnt(4) would NOT
//              guarantee B(NT-1)! Tail drain: vmcnt(0).  [round-2 bug]
// LDS swizzle: phys 16B-slot = slot ^ (row&7)  (both sides, rule #21).

__global__ __launch_bounds__(512, 2) void qlin_gemm_kernel(
    const u16* __restrict__ A,        // [M][K]
    const u16* __restrict__ B,        // [N][K]
    const float* __restrict__ rowsum, // [M]
    const float* __restrict__ scale,  // [N]
    const float* __restrict__ zp,     // [N]
    const float* __restrict__ bias,   // [N]
    float* __restrict__ out) {        // [M][N]
  extern __shared__ u16 lds[];
  u16* Al = lds;          // [2][256][64]
  u16* Bl = lds + 32768;  // [2][256][64]

  const int tid = threadIdx.x;
  const int lane = tid & 63;
  const int wave = tid >> 6;
  const int wm = wave >> 2;  // 0..1
  const int wn = wave & 3;   // 0..3

  // T1: bijective XCD swizzle (512 wgs, 512%8==0 -> simple form)
  const int bid = blockIdx.x;
  const int swz = (bid & 7) * 64 + (bid >> 3);
  const int bm = swz >> 4;   // 0..31
  const int bn = swz & 15;   // 0..15
  const int row0 = bm * 256, col0 = bn * 256;

  // staging: thread t -> row (t>>3) within 64-row issue block, slot t&7,
  // global col pre-swizzled: slot^(row&7). LDS dest is WAVE-UNIFORM base;
  // HW writes lane i at base + i*16 (m104 contract).
  const int sr = tid >> 3;
  const int ss = (tid & 7) ^ (sr & 7);
  const u16* Ags = A + (size_t)(row0 + sr) * KDIM + ss * 8;
  const u16* Bgs = B + (size_t)(col0 + sr) * KDIM + ss * 8;
  u16* Ald = Al + wave * 512;  // 64 lanes x 8 u16
  u16* Bld = Bl + wave * 512;

#define STAGE_A(d, tau, h)                                                    \
  do {                                                                        \
    const u16* _g = Ags + (size_t)(h) * 128 * KDIM + (tau) * 64;             \
    u16* _l = Ald + (d) * 16384 + (h) * 8192;                                \
    GLDS(_g, _l);                                                            \
    GLDS(_g + (size_t)64 * KDIM, _l + 4096);                                 \
  } while (0)

#define STAGE_B(d, tau, h)                                                    \
  do {                                                                        \
    const u16* _g = Bgs + (size_t)(h) * 128 * KDIM + (tau) * 64;             \
    u16* _l = Bld + (d) * 16384 + (h) * 8192;                                \
    GLDS(_g, _l);                                                            \
    GLDS(_g + (size_t)64 * KDIM, _l + 4096);                                 \
  } while (0)

  // ds_read fragment addressing (swizzled): lane reads logical
  // (row = <dim0>+r, colbyte = ks*64 + g*16) at colbyte ^ ((row&7)<<4).
  const int r = lane & 15;
  const int g = lane >> 4;
  const int swzx = (lane & 7) << 4;                // == (row&7)<<4, row≡r mod 8
  const int ce0 = ((g * 16) ^ swzx) >> 1;          // u16 elems, ks=0
  const int ce1 = ((64 + g * 16) ^ swzx) >> 1;     // u16 elems, ks=1
  const u16* Ar = Al + (wm * 128 + r) * 64;
  const u16* Br = Bl + (wn * 64 + r) * 64;

#define LDA(m, ks) (*(const bf16x8*)(Ard + (m) * 1024 + ((ks) ? ce1 : ce0)))
#define LDB(n, ks) (*(const bf16x8*)(Brd + (n) * 1024 + ((ks) ? ce1 : ce0)))
#define MFMA(d, va, vb) \
  d = __builtin_amdgcn_mfma_f32_16x16x32_bf16(va, vb, d, 0, 0, 0)

  f32x4 acc[8][4] = {};
  bf16x8 a[8][2], b[4][2];

  // prologue: A(0), B(0), A(1); vmcnt(4) -> tile0 landed, A(1) in flight
  STAGE_A(0, 0, 0); STAGE_A(0, 0, 1);
  STAGE_B(0, 0, 0); STAGE_B(0, 0, 1);
  STAGE_A(1, 1, 0); STAGE_A(1, 1, 1);
  asm volatile("s_waitcnt vmcnt(4)" ::: "memory");
  __builtin_amdgcn_s_barrier();

  for (int t = 0; t < NT; ++t) {
    const int d = t & 1;
    const u16* Ard = Ar + d * 16384;
    const u16* Brd = Br + d * 16384;

    // ---- phase 0: ds-read a0-3,b0-1 | stage B(t+1)h0 | MFMA m0-3 x n0-1 ----
#pragma unroll
    for (int m = 0; m < 4; ++m) { a[m][0] = LDA(m, 0); a[m][1] = LDA(m, 1); }
#pragma unroll
    for (int n = 0; n < 2; ++n) { b[n][0] = LDB(n, 0); b[n][1] = LDB(n, 1); }
    if (t + 1 < NT) STAGE_B(d ^ 1, t + 1, 0);
    __builtin_amdgcn_s_barrier();
    asm volatile("s_waitcnt lgkmcnt(0)" ::: "memory");
    __builtin_amdgcn_s_setprio(1);
#pragma unroll
    for (int m = 0; m < 4; ++m)
#pragma unroll
      for (int n = 0; n < 2; ++n) {
        MFMA(acc[m][n], a[m][0], b[n][0]);
        MFMA(acc[m][n], a[m][1], b[n][1]);
      }
    __builtin_amdgcn_s_setprio(0);
    __builtin_amdgcn_s_barrier();

    // ---- phase 1: ds-read b2-3,a4-7 | stage B(t+1)h1 | MFMA m0-3 x n2-3 ----
#pragma unroll
    for (int n = 2; n < 4; ++n) { b[n][0] = LDB(n, 0); b[n][1] = LDB(n, 1); }
#pragma unroll
    for (int m = 4; m < 8; ++m) { a[m][0] = LDA(m, 0); a[m][1] = LDA(m, 1); }
    if (t + 1 < NT) STAGE_B(d ^ 1, t + 1, 1);
    __builtin_amdgcn_s_barrier();
    asm volatile("s_waitcnt lgkmcnt(0)" ::: "memory");
    __builtin_amdgcn_s_setprio(1);
#pragma unroll
    for (int m = 0; m < 4; ++m)
#pragma unroll
      for (int n = 2; n < 4; ++n) {
        MFMA(acc[m][n], a[m][0], b[n][0]);
        MFMA(acc[m][n], a[m][1], b[n][1]);
      }
    __builtin_amdgcn_s_setprio(0);
    __builtin_amdgcn_s_barrier();
    // all waves' ds_reads of buf d done (each passed its lgkmcnt(0)) -> A buf
    // d may now be overwritten.

    // ---- phase 2: stage A(t+2)h0 into buf d | MFMA m4-7 x n0-1 ----
    if (t + 2 < NT) STAGE_A(d, t + 2, 0);
    __builtin_amdgcn_s_barrier();
    __builtin_amdgcn_s_setprio(1);
#pragma unroll
    for (int m = 4; m < 8; ++m)
#pragma unroll
      for (int n = 0; n < 2; ++n) {
        MFMA(acc[m][n], a[m][0], b[n][0]);
        MFMA(acc[m][n], a[m][1], b[n][1]);
      }
    __builtin_amdgcn_s_setprio(0);
    __builtin_amdgcn_s_barrier();

    // ---- phase 3: stage A(t+2)h1 | MFMA m4-7 x n2-3 | tile-end wait ----
    if (t + 2 < NT) STAGE_A(d, t + 2, 1);
    __builtin_amdgcn_s_barrier();
    __builtin_amdgcn_s_setprio(1);
#pragma unroll
    for (int m = 4; m < 8; ++m)
#pragma unroll
      for (int n = 2; n < 4; ++n) {
        MFMA(acc[m][n], a[m][0], b[n][0]);
        MFMA(acc[m][n], a[m][1], b[n][1]);
      }
    __builtin_amdgcn_s_setprio(0);
    if (t < NT - 2) {
      asm volatile("s_waitcnt vmcnt(4)" ::: "memory");  // steady: 12 -> 4
    } else {
      asm volatile("s_waitcnt vmcnt(0)" ::: "memory");  // tail drain
    }
    __builtin_amdgcn_s_barrier();
  }

  // epilogue: C/D layout col=lane&15 (=r), row=(lane>>4)*4+reg (=g*4+q)
  const int r0g = row0 + wm * 128 + g * 4;
  const int c0g = col0 + wn * 64 + r;
#pragma unroll
  for (int n = 0; n < 4; ++n) {
    const int col = c0g + n * 16;
    const float s = scale[col];
    const float szp = s * zp[col];
    const float bz = bias[col];
#pragma unroll
    for (int m = 0; m < 8; ++m) {
      const int row = r0g + m * 16;
#pragma unroll
      for (int q = 0; q < 4; ++q) {
        out[(size_t)(row + q) * NDIM + col] =
            s * acc[m][n][q] - szp * rowsum[row + q] + bz;
      }
    }
  }
#undef STAGE_A
#undef STAGE_B
#undef LDA
#undef LDB
#undef MFMA
}

// --- launch ------------------------------------------------------------------

extern "C" void kernel_launch(void* const* d_in, const int* in_sizes, int n_in,
                              void* d_out, int out_size, void* d_ws,
                              size_t ws_size, hipStream_t stream) {
  const float* x = (const float*)d_in[0];
  const int* wq = (const int*)d_in[1];
  const float* scale = (const float*)d_in[2];
  const float* zp = (const float*)d_in[3];
  const float* bias = (const float*)d_in[4];
  float* out = (float*)d_out;

  char* ws = (char*)d_ws;
  u16* xb = (u16*)ws;                                   // 64 MiB
  u16* wb = (u16*)(ws + (size_t)M_TOK * KDIM * 2);      // 32 MiB
  float* rowsum = (float*)(ws + (size_t)M_TOK * KDIM * 2 +
                           (size_t)NDIM * KDIM * 2);    // 32 KiB

  // 128 KiB dynamic LDS: raise the cap (idempotent, not a stream op)
  hipFuncSetAttribute((const void*)qlin_gemm_kernel,
                      hipFuncAttributeMaxDynamicSharedMemorySize, 131072);

  convert_x_kernel<<<M_TOK, 256, 0, stream>>>(x, xb, rowsum);
  convert_w_kernel<<<(NDIM * (size_t)KDIM) / (256 * 8), 256, 0, stream>>>(wq, wb);

  qlin_gemm_kernel<<<dim3((M_TOK / 256) * (NDIM / 256)), dim3(512), 131072,
                     stream>>>(xb, wb, rowsum, scale, zp, bias, out);
}

// Round 4
// 279.838 us; speedup vs baseline: 1.2065x; 1.0410x over previous
//
#include <hip/hip_runtime.h>

// ---------------------------------------------------------------------------
// QuantizedLinear: y = x @ ((q - zp)*s)^T + bias
// Decomposition: y[m,o] = s[o]*G[m,o] - s[o]*zp[o]*rowsum[m] + bias[o]
//   G = x_bf16 @ q_bf16^T   (bf16 MFMA; q in [0,255) is EXACT in bf16)
// GEMM: 256x256 8-phase template (m201): BK=64, 8 waves (2Mx4N), 128 KiB
// dbuf LDS, counted vmcnt (4 steady / 0 tail drain), T2 st-swizzle,
// T5 setprio, T1 XCD swizzle. Round 4: vectorized transpose epilogue
// (LDS round-trip -> coalesced global_store_dwordx4).
// ---------------------------------------------------------------------------

typedef unsigned short u16;
typedef __attribute__((ext_vector_type(8))) short bf16x8;
typedef __attribute__((ext_vector_type(8))) u16 u16x8;
typedef __attribute__((ext_vector_type(4))) float f32x4;

#define M_TOK 8192
#define KDIM 4096
#define NDIM 4096
#define NT (KDIM / 64)  // 64 K-tiles

// --- helpers ---------------------------------------------------------------

__device__ __forceinline__ u16 f32_to_bf16_rne(float f) {
  unsigned u = __float_as_uint(f);
  unsigned r = u + 0x7FFFu + ((u >> 16) & 1u);
  return (u16)(r >> 16);
}

__device__ __forceinline__ u16 i32_to_bf16(int v) {
  return (u16)(__float_as_uint((float)v) >> 16);  // exact for 0..255
}

#define GLDS(gptr, lptr)                                                      \
  __builtin_amdgcn_global_load_lds(                                          \
      (const __attribute__((address_space(1))) void*)(gptr),                 \
      (__attribute__((address_space(3))) void*)(lptr), 16, 0, 0)

// --- kernel 1: x f32 -> bf16, fused row-sum (of the ROUNDED values) --------

__global__ __launch_bounds__(256) void convert_x_kernel(
    const float* __restrict__ x, u16* __restrict__ xb,
    float* __restrict__ rowsum) {
  const int row = blockIdx.x;
  const int tid = threadIdx.x;
  const float* xr = x + (size_t)row * KDIM;
  u16* xbr = xb + (size_t)row * KDIM;
  float acc = 0.f;
#pragma unroll
  for (int i = 0; i < 2; ++i) {
    const int e = (i * 256 + tid) * 8;
    const float4 a = *(const float4*)(xr + e);
    const float4 b = *(const float4*)(xr + e + 4);
    float v[8] = {a.x, a.y, a.z, a.w, b.x, b.y, b.z, b.w};
    u16x8 o;
#pragma unroll
    for (int j = 0; j < 8; ++j) {
      const u16 h = f32_to_bf16_rne(v[j]);
      o[j] = (u16)h;
      acc += __uint_as_float((unsigned)h << 16);
    }
    *(u16x8*)(xbr + e) = o;
  }
#pragma unroll
  for (int off = 32; off > 0; off >>= 1) acc += __shfl_down(acc, off, 64);
  __shared__ float red[4];
  if ((tid & 63) == 0) red[tid >> 6] = acc;
  __syncthreads();
  if (tid == 0) rowsum[row] = red[0] + red[1] + red[2] + red[3];
}

// --- kernel 2: w int32 -> bf16 (exact) --------------------------------------

__global__ __launch_bounds__(256) void convert_w_kernel(
    const int* __restrict__ wq, u16* __restrict__ wb) {
  const size_t idx = (size_t)blockIdx.x * 256 + threadIdx.x;
  const int4* src = (const int4*)wq + idx * 2;
  const int4 a = src[0];
  const int4 b = src[1];
  u16x8 o;
  o[0] = i32_to_bf16(a.x); o[1] = i32_to_bf16(a.y);
  o[2] = i32_to_bf16(a.z); o[3] = i32_to_bf16(a.w);
  o[4] = i32_to_bf16(b.x); o[5] = i32_to_bf16(b.y);
  o[6] = i32_to_bf16(b.z); o[7] = i32_to_bf16(b.w);
  *((u16x8*)wb + idx) = o;
}

// --- kernel 3: 256x256 8-phase bf16 GEMM, fused dequant epilogue ------------
// LDS: Al[2][256][64], Bl[2][256][64] bf16 = 128 KiB (dynamic).
// Stage schedule (tile t): p0:B(t+1)h0  p1:B(t+1)h1  p2:A(t+2)h0  p3:A(t+2)h1
// Tile-end wait: steady vmcnt(4); last two tiles vmcnt(0) (tail drain).
// LDS swizzle: phys 16B-slot = slot ^ (row&7)  (both sides, rule #21).
// Epilogue: per-wave private LDS transpose (32x68 f32 chunks, stride 68 =
// 2-way write aliasing = free) -> coalesced f32x4 stores, float4 dequant.

__global__ __launch_bounds__(512, 2) void qlin_gemm_kernel(
    const u16* __restrict__ A,        // [M][K]
    const u16* __restrict__ B,        // [N][K]
    const float* __restrict__ rowsum, // [M]
    const float* __restrict__ scale,  // [N]
    const float* __restrict__ zp,     // [N]
    const float* __restrict__ bias,   // [N]
    float* __restrict__ out) {        // [M][N]
  extern __shared__ u16 lds[];
  u16* Al = lds;          // [2][256][64]
  u16* Bl = lds + 32768;  // [2][256][64]

  const int tid = threadIdx.x;
  const int lane = tid & 63;
  const int wave = tid >> 6;
  const int wm = wave >> 2;  // 0..1
  const int wn = wave & 3;   // 0..3

  // T1: bijective XCD swizzle (512 wgs, 512%8==0 -> simple form)
  const int bid = blockIdx.x;
  const int swz = (bid & 7) * 64 + (bid >> 3);
  const int bm = swz >> 4;   // 0..31
  const int bn = swz & 15;   // 0..15
  const int row0 = bm * 256, col0 = bn * 256;

  // staging: thread t -> row (t>>3), slot t&7, global col pre-swizzled.
  // LDS dest is WAVE-UNIFORM base; HW writes lane i at base + i*16 (m104).
  const int sr = tid >> 3;
  const int ss = (tid & 7) ^ (sr & 7);
  const u16* Ags = A + (size_t)(row0 + sr) * KDIM + ss * 8;
  const u16* Bgs = B + (size_t)(col0 + sr) * KDIM + ss * 8;
  u16* Ald = Al + wave * 512;
  u16* Bld = Bl + wave * 512;

#define STAGE_A(d, tau, h)                                                    \
  do {                                                                        \
    const u16* _g = Ags + (size_t)(h) * 128 * KDIM + (tau) * 64;             \
    u16* _l = Ald + (d) * 16384 + (h) * 8192;                                \
    GLDS(_g, _l);                                                            \
    GLDS(_g + (size_t)64 * KDIM, _l + 4096);                                 \
  } while (0)

#define STAGE_B(d, tau, h)                                                    \
  do {                                                                        \
    const u16* _g = Bgs + (size_t)(h) * 128 * KDIM + (tau) * 64;             \
    u16* _l = Bld + (d) * 16384 + (h) * 8192;                                \
    GLDS(_g, _l);                                                            \
    GLDS(_g + (size_t)64 * KDIM, _l + 4096);                                 \
  } while (0)

  // ds_read fragment addressing (swizzled): lane reads logical
  // (row = <dim0>+r, colbyte = ks*64 + g*16) at colbyte ^ ((row&7)<<4).
  const int r = lane & 15;
  const int g = lane >> 4;
  const int swzx = (lane & 7) << 4;                // == (row&7)<<4
  const int ce0 = ((g * 16) ^ swzx) >> 1;          // u16 elems, ks=0
  const int ce1 = ((64 + g * 16) ^ swzx) >> 1;     // u16 elems, ks=1
  const u16* Ar = Al + (wm * 128 + r) * 64;
  const u16* Br = Bl + (wn * 64 + r) * 64;

#define LDA(m, ks) (*(const bf16x8*)(Ard + (m) * 1024 + ((ks) ? ce1 : ce0)))
#define LDB(n, ks) (*(const bf16x8*)(Brd + (n) * 1024 + ((ks) ? ce1 : ce0)))
#define MFMA(d, va, vb) \
  d = __builtin_amdgcn_mfma_f32_16x16x32_bf16(va, vb, d, 0, 0, 0)

  f32x4 acc[8][4] = {};
  bf16x8 a[8][2], b[4][2];

  // prologue: A(0), B(0), A(1); vmcnt(4) -> tile0 landed, A(1) in flight
  STAGE_A(0, 0, 0); STAGE_A(0, 0, 1);
  STAGE_B(0, 0, 0); STAGE_B(0, 0, 1);
  STAGE_A(1, 1, 0); STAGE_A(1, 1, 1);
  asm volatile("s_waitcnt vmcnt(4)" ::: "memory");
  __builtin_amdgcn_s_barrier();

  for (int t = 0; t < NT; ++t) {
    const int d = t & 1;
    const u16* Ard = Ar + d * 16384;
    const u16* Brd = Br + d * 16384;

    // ---- phase 0: ds-read a0-3,b0-1 | stage B(t+1)h0 | MFMA m0-3 x n0-1 ----
#pragma unroll
    for (int m = 0; m < 4; ++m) { a[m][0] = LDA(m, 0); a[m][1] = LDA(m, 1); }
#pragma unroll
    for (int n = 0; n < 2; ++n) { b[n][0] = LDB(n, 0); b[n][1] = LDB(n, 1); }
    if (t + 1 < NT) STAGE_B(d ^ 1, t + 1, 0);
    __builtin_amdgcn_s_barrier();
    asm volatile("s_waitcnt lgkmcnt(0)" ::: "memory");
    __builtin_amdgcn_s_setprio(1);
#pragma unroll
    for (int m = 0; m < 4; ++m)
#pragma unroll
      for (int n = 0; n < 2; ++n) {
        MFMA(acc[m][n], a[m][0], b[n][0]);
        MFMA(acc[m][n], a[m][1], b[n][1]);
      }
    __builtin_amdgcn_s_setprio(0);
    __builtin_amdgcn_s_barrier();

    // ---- phase 1: ds-read b2-3,a4-7 | stage B(t+1)h1 | MFMA m0-3 x n2-3 ----
#pragma unroll
    for (int n = 2; n < 4; ++n) { b[n][0] = LDB(n, 0); b[n][1] = LDB(n, 1); }
#pragma unroll
    for (int m = 4; m < 8; ++m) { a[m][0] = LDA(m, 0); a[m][1] = LDA(m, 1); }
    if (t + 1 < NT) STAGE_B(d ^ 1, t + 1, 1);
    __builtin_amdgcn_s_barrier();
    asm volatile("s_waitcnt lgkmcnt(0)" ::: "memory");
    __builtin_amdgcn_s_setprio(1);
#pragma unroll
    for (int m = 0; m < 4; ++m)
#pragma unroll
      for (int n = 2; n < 4; ++n) {
        MFMA(acc[m][n], a[m][0], b[n][0]);
        MFMA(acc[m][n], a[m][1], b[n][1]);
      }
    __builtin_amdgcn_s_setprio(0);
    __builtin_amdgcn_s_barrier();

    // ---- phase 2: stage A(t+2)h0 into buf d | MFMA m4-7 x n0-1 ----
    if (t + 2 < NT) STAGE_A(d, t + 2, 0);
    __builtin_amdgcn_s_barrier();
    __builtin_amdgcn_s_setprio(1);
#pragma unroll
    for (int m = 4; m < 8; ++m)
#pragma unroll
      for (int n = 0; n < 2; ++n) {
        MFMA(acc[m][n], a[m][0], b[n][0]);
        MFMA(acc[m][n], a[m][1], b[n][1]);
      }
    __builtin_amdgcn_s_setprio(0);
    __builtin_amdgcn_s_barrier();

    // ---- phase 3: stage A(t+2)h1 | MFMA m4-7 x n2-3 | tile-end wait ----
    if (t + 2 < NT) STAGE_A(d, t + 2, 1);
    __builtin_amdgcn_s_barrier();
    __builtin_amdgcn_s_setprio(1);
#pragma unroll
    for (int m = 4; m < 8; ++m)
#pragma unroll
      for (int n = 2; n < 4; ++n) {
        MFMA(acc[m][n], a[m][0], b[n][0]);
        MFMA(acc[m][n], a[m][1], b[n][1]);
      }
    __builtin_amdgcn_s_setprio(0);
    if (t < NT - 2) {
      asm volatile("s_waitcnt vmcnt(4)" ::: "memory");  // steady: 12 -> 4
    } else {
      asm volatile("s_waitcnt vmcnt(0)" ::: "memory");  // tail drain
    }
    __builtin_amdgcn_s_barrier();
  }

  // --- epilogue: per-wave LDS transpose -> coalesced f32x4 stores ----------
  // acc[m][n][q] is output (rowlocal = m*16 + g*4 + q, collocal = n*16 + r)
  // of the wave's 128x64 subtile. 4 chunks of 32 rows through a private
  // 32x68-f32 LDS region (stride 68: write bank = (16g+4q+r+..)%32 -> exactly
  // 2-way = free). Reads: 16 lanes span a full 256B row = canonical pattern.
  {
    const int wrow0 = row0 + wm * 128;
    const int wcol0 = col0 + wn * 64;
    float* eps = (float*)lds + wave * 2176;  // 32*68 f32 = 8704 B, private
    const f32x4 s4 = *(const f32x4*)(scale + wcol0 + 4 * r);
    const f32x4 z4 = *(const f32x4*)(zp + wcol0 + 4 * r);
    const f32x4 b4 = *(const f32x4*)(bias + wcol0 + 4 * r);
    const f32x4 szp4 = s4 * z4;
#pragma unroll
    for (int c = 0; c < 4; ++c) {
#pragma unroll
      for (int mm = 0; mm < 2; ++mm)
#pragma unroll
        for (int n = 0; n < 4; ++n)
#pragma unroll
          for (int q = 0; q < 4; ++q)
            eps[(mm * 16 + g * 4 + q) * 68 + n * 16 + r] =
                acc[2 * c + mm][n][q];
      asm volatile("s_waitcnt lgkmcnt(0)" ::: "memory");
#pragma unroll
      for (int j = 0; j < 8; ++j) {
        const int rl = j * 4 + g;                 // 0..31
        const int grow = wrow0 + c * 32 + rl;
        const f32x4 v = *(const f32x4*)(eps + rl * 68 + 4 * r);
        const float rs = rowsum[grow];
        const f32x4 o4 = s4 * v - szp4 * rs + b4;
        *(f32x4*)(out + (size_t)grow * NDIM + wcol0 + 4 * r) = o4;
      }
      asm volatile("s_waitcnt lgkmcnt(0)" ::: "memory");  // WAR before reuse
    }
  }
#undef STAGE_A
#undef STAGE_B
#undef LDA
#undef LDB
#undef MFMA
}

// --- launch ------------------------------------------------------------------

extern "C" void kernel_launch(void* const* d_in, const int* in_sizes, int n_in,
                              void* d_out, int out_size, void* d_ws,
                              size_t ws_size, hipStream_t stream) {
  const float* x = (const float*)d_in[0];
  const int* wq = (const int*)d_in[1];
  const float* scale = (const float*)d_in[2];
  const float* zp = (const float*)d_in[3];
  const float* bias = (const float*)d_in[4];
  float* out = (float*)d_out;

  char* ws = (char*)d_ws;
  u16* xb = (u16*)ws;                                   // 64 MiB
  u16* wb = (u16*)(ws + (size_t)M_TOK * KDIM * 2);      // 32 MiB
  float* rowsum = (float*)(ws + (size_t)M_TOK * KDIM * 2 +
                           (size_t)NDIM * KDIM * 2);    // 32 KiB

  // 128 KiB dynamic LDS: raise the cap (idempotent, not a stream op)
  hipFuncSetAttribute((const void*)qlin_gemm_kernel,
                      hipFuncAttributeMaxDynamicSharedMemorySize, 131072);

  convert_x_kernel<<<M_TOK, 256, 0, stream>>>(x, xb, rowsum);
  convert_w_kernel<<<(NDIM * (size_t)KDIM) / (256 * 8), 256, 0, stream>>>(wq, wb);

  qlin_gemm_kernel<<<dim3((M_TOK / 256) * (NDIM / 256)), dim3(512), 131072,
                     stream>>>(xb, wb, rowsum, scale, zp, bias, out);
}

// Round 5
// 277.464 us; speedup vs baseline: 1.2168x; 1.0086x over previous
//
#include <hip/hip_runtime.h>

// ---------------------------------------------------------------------------
// QuantizedLinear: y = x @ ((q - zp)*s)^T + bias
// Decomposition: y[m,o] = s[o]*G[m,o] - s[o]*zp[o]*rowsum[m] + bias[o]
//   G = x_bf16 @ q_bf16^T   (bf16 MFMA; q in [0,255) is EXACT in bf16)
// GEMM: 256x256 8-phase template (m201): BK=64, 8 waves (2Mx4N), 128 KiB
// dbuf LDS, counted vmcnt, T2 st-swizzle, T5 setprio, T1 XCD swizzle.
// Round 5: fragment-level software pipeline — ds_reads spread 8/8/0/8 across
// phases with COUNTED lgkm waits (m196/m201 interleave), next-tile a0-3
// prefetched in phase 3.
// ---------------------------------------------------------------------------

typedef unsigned short u16;
typedef __attribute__((ext_vector_type(8))) short bf16x8;
typedef __attribute__((ext_vector_type(8))) u16 u16x8;
typedef __attribute__((ext_vector_type(4))) float f32x4;

#define M_TOK 8192
#define KDIM 4096
#define NDIM 4096
#define NT (KDIM / 64)  // 64 K-tiles

// --- helpers ---------------------------------------------------------------

__device__ __forceinline__ u16 f32_to_bf16_rne(float f) {
  unsigned u = __float_as_uint(f);
  unsigned r = u + 0x7FFFu + ((u >> 16) & 1u);
  return (u16)(r >> 16);
}

__device__ __forceinline__ u16 i32_to_bf16(int v) {
  return (u16)(__float_as_uint((float)v) >> 16);  // exact for 0..255
}

#define GLDS(gptr, lptr)                                                      \
  __builtin_amdgcn_global_load_lds(                                          \
      (const __attribute__((address_space(1))) void*)(gptr),                 \
      (__attribute__((address_space(3))) void*)(lptr), 16, 0, 0)

// --- kernel 1: x f32 -> bf16, fused row-sum (of the ROUNDED values) --------

__global__ __launch_bounds__(256) void convert_x_kernel(
    const float* __restrict__ x, u16* __restrict__ xb,
    float* __restrict__ rowsum) {
  const int row = blockIdx.x;
  const int tid = threadIdx.x;
  const float* xr = x + (size_t)row * KDIM;
  u16* xbr = xb + (size_t)row * KDIM;
  float acc = 0.f;
#pragma unroll
  for (int i = 0; i < 2; ++i) {
    const int e = (i * 256 + tid) * 8;
    const float4 a = *(const float4*)(xr + e);
    const float4 b = *(const float4*)(xr + e + 4);
    float v[8] = {a.x, a.y, a.z, a.w, b.x, b.y, b.z, b.w};
    u16x8 o;
#pragma unroll
    for (int j = 0; j < 8; ++j) {
      const u16 h = f32_to_bf16_rne(v[j]);
      o[j] = (u16)h;
      acc += __uint_as_float((unsigned)h << 16);
    }
    *(u16x8*)(xbr + e) = o;
  }
#pragma unroll
  for (int off = 32; off > 0; off >>= 1) acc += __shfl_down(acc, off, 64);
  __shared__ float red[4];
  if ((tid & 63) == 0) red[tid >> 6] = acc;
  __syncthreads();
  if (tid == 0) rowsum[row] = red[0] + red[1] + red[2] + red[3];
}

// --- kernel 2: w int32 -> bf16 (exact) --------------------------------------

__global__ __launch_bounds__(256) void convert_w_kernel(
    const int* __restrict__ wq, u16* __restrict__ wb) {
  const size_t idx = (size_t)blockIdx.x * 256 + threadIdx.x;
  const int4* src = (const int4*)wq + idx * 2;
  const int4 a = src[0];
  const int4 b = src[1];
  u16x8 o;
  o[0] = i32_to_bf16(a.x); o[1] = i32_to_bf16(a.y);
  o[2] = i32_to_bf16(a.z); o[3] = i32_to_bf16(a.w);
  o[4] = i32_to_bf16(b.x); o[5] = i32_to_bf16(b.y);
  o[6] = i32_to_bf16(b.z); o[7] = i32_to_bf16(b.w);
  *((u16x8*)wb + idx) = o;
}

// --- kernel 3: 256x256 pipelined bf16 GEMM, fused dequant epilogue ----------
// LDS: Al[2][256][64], Bl[2][256][64] bf16 = 128 KiB (dynamic).
// Per-tile phases (quadrants q0..q3 of the wave's 128x64 output):
//  p0: read b0-1,b2-3(cur) | stage B(t+1)h0 | bar | lgkm(4)  | q0 (a0-3 x b0-1)
//  p1: read a4-7(cur)      | stage B(t+1)h1 | bar | lgkm(8)  | q1 (a0-3 x b2-3)
//  p2: vmcnt(4): A(t+1) landed              | bar | lgkm(0)  | q2 (a4-7 x b0-1)
//  p3: read a0-3(NEXT buf) | stage A(t+2)h0+h1 | bar |       | q3 (a4-7 x b2-3)
//      then vmcnt(4) (B(t+1) landed; A(t+2) in flight); vmcnt(0) at t>=NT-2.
// In-order DS completion makes counted lgkm valid; b0-1-before-b2-3 order is
// pinned by an empty asm memory fence. WAR ledger: all reads of a region are
// consumed (waited) >=1 barrier before any GLDS overwrites it.
// LDS swizzle: phys 16B-slot = slot ^ (row&7) (both sides, rule #21).

__global__ __launch_bounds__(512, 2) void qlin_gemm_kernel(
    const u16* __restrict__ A,        // [M][K]
    const u16* __restrict__ B,        // [N][K]
    const float* __restrict__ rowsum, // [M]
    const float* __restrict__ scale,  // [N]
    const float* __restrict__ zp,     // [N]
    const float* __restrict__ bias,   // [N]
    float* __restrict__ out) {        // [M][N]
  extern __shared__ u16 lds[];
  u16* Al = lds;          // [2][256][64]
  u16* Bl = lds + 32768;  // [2][256][64]

  const int tid = threadIdx.x;
  const int lane = tid & 63;
  const int wave = tid >> 6;
  const int wm = wave >> 2;  // 0..1
  const int wn = wave & 3;   // 0..3

  // T1: bijective XCD swizzle (512 wgs, 512%8==0 -> simple form)
  const int bid = blockIdx.x;
  const int swz = (bid & 7) * 64 + (bid >> 3);
  const int bm = swz >> 4;   // 0..31
  const int bn = swz & 15;   // 0..15
  const int row0 = bm * 256, col0 = bn * 256;

  // staging: thread t -> row (t>>3), slot t&7, global col pre-swizzled.
  // LDS dest is WAVE-UNIFORM base; HW writes lane i at base + i*16 (m104).
  const int sr = tid >> 3;
  const int ss = (tid & 7) ^ (sr & 7);
  const u16* Ags = A + (size_t)(row0 + sr) * KDIM + ss * 8;
  const u16* Bgs = B + (size_t)(col0 + sr) * KDIM + ss * 8;
  u16* Ald = Al + wave * 512;
  u16* Bld = Bl + wave * 512;

#define STAGE_A(d, tau, h)                                                    \
  do {                                                                        \
    const u16* _g = Ags + (size_t)(h) * 128 * KDIM + (tau) * 64;             \
    u16* _l = Ald + (d) * 16384 + (h) * 8192;                                \
    GLDS(_g, _l);                                                            \
    GLDS(_g + (size_t)64 * KDIM, _l + 4096);                                 \
  } while (0)

#define STAGE_B(d, tau, h)                                                    \
  do {                                                                        \
    const u16* _g = Bgs + (size_t)(h) * 128 * KDIM + (tau) * 64;             \
    u16* _l = Bld + (d) * 16384 + (h) * 8192;                                \
    GLDS(_g, _l);                                                            \
    GLDS(_g + (size_t)64 * KDIM, _l + 4096);                                 \
  } while (0)

  // ds_read fragment addressing (swizzled): lane reads logical
  // (row = <dim0>+r, colbyte = ks*64 + g*16) at colbyte ^ ((row&7)<<4).
  const int r = lane & 15;
  const int g = lane >> 4;
  const int swzx = (lane & 7) << 4;                // == (row&7)<<4
  const int ce0 = ((g * 16) ^ swzx) >> 1;          // u16 elems, ks=0
  const int ce1 = ((64 + g * 16) ^ swzx) >> 1;     // u16 elems, ks=1
  const u16* Ar = Al + (wm * 128 + r) * 64;
  const u16* Br = Bl + (wn * 64 + r) * 64;

#define LDA(base, m, ks) \
  (*(const bf16x8*)((base) + (m) * 1024 + ((ks) ? ce1 : ce0)))
#define LDB(base, n, ks) \
  (*(const bf16x8*)((base) + (n) * 1024 + ((ks) ? ce1 : ce0)))
#define MFMA(d, va, vb) \
  d = __builtin_amdgcn_mfma_f32_16x16x32_bf16(va, vb, d, 0, 0, 0)

  f32x4 acc[8][4] = {};
  bf16x8 a[8][2], b[4][2];

  // prologue: A(0), B(0), A(1); vmcnt(4) -> tile0 landed, A(1) in flight;
  // then prefetch a0-3 of tile 0 (b-frags read in tile 0's p0).
  STAGE_A(0, 0, 0); STAGE_A(0, 0, 1);
  STAGE_B(0, 0, 0); STAGE_B(0, 0, 1);
  STAGE_A(1, 1, 0); STAGE_A(1, 1, 1);
  asm volatile("s_waitcnt vmcnt(4)" ::: "memory");
  __builtin_amdgcn_s_barrier();
#pragma unroll
  for (int m = 0; m < 4; ++m) {
    a[m][0] = LDA(Ar, m, 0); a[m][1] = LDA(Ar, m, 1);
  }

  for (int t = 0; t < NT; ++t) {
    const int d = t & 1;
    const u16* Ard = Ar + d * 16384;
    const u16* Brd = Br + d * 16384;
    const u16* ArdN = Ar + (d ^ 1) * 16384;

    // ---- p0: read b0-1 | fence | b2-3 | stage B(t+1)h0 | lgkm(4) | q0 ----
#pragma unroll
    for (int n = 0; n < 2; ++n) {
      b[n][0] = LDB(Brd, n, 0); b[n][1] = LDB(Brd, n, 1);
    }
    asm volatile("" ::: "memory");  // pin b0-1 before b2-3 (counted lgkm)
#pragma unroll
    for (int n = 2; n < 4; ++n) {
      b[n][0] = LDB(Brd, n, 0); b[n][1] = LDB(Brd, n, 1);
    }
    if (t + 1 < NT) STAGE_B(d ^ 1, t + 1, 0);
    __builtin_amdgcn_s_barrier();
    asm volatile("s_waitcnt lgkmcnt(4)" ::: "memory");  // a0-3,b0-1 ready
    __builtin_amdgcn_s_setprio(1);
#pragma unroll
    for (int m = 0; m < 4; ++m)
#pragma unroll
      for (int n = 0; n < 2; ++n) {
        MFMA(acc[m][n], a[m][0], b[n][0]);
        MFMA(acc[m][n], a[m][1], b[n][1]);
      }
    __builtin_amdgcn_s_setprio(0);
    __builtin_amdgcn_s_barrier();

    // ---- p1: read a4-7 | stage B(t+1)h1 | lgkm(8) | q1 ----
#pragma unroll
    for (int m = 4; m < 8; ++m) {
      a[m][0] = LDA(Ard, m, 0); a[m][1] = LDA(Ard, m, 1);
    }
    if (t + 1 < NT) STAGE_B(d ^ 1, t + 1, 1);
    __builtin_amdgcn_s_barrier();
    asm volatile("s_waitcnt lgkmcnt(8)" ::: "memory");  // b2-3 ready
    __builtin_amdgcn_s_setprio(1);
#pragma unroll
    for (int m = 0; m < 4; ++m)
#pragma unroll
      for (int n = 2; n < 4; ++n) {
        MFMA(acc[m][n], a[m][0], b[n][0]);
        MFMA(acc[m][n], a[m][1], b[n][1]);
      }
    __builtin_amdgcn_s_setprio(0);
    __builtin_amdgcn_s_barrier();

    // ---- p2: vmcnt(4): A(t+1) landed | lgkm(0): a4-7 ready | q2 ----
    if (t + 1 < NT) {
      asm volatile("s_waitcnt vmcnt(4)" ::: "memory");
    }
    __builtin_amdgcn_s_barrier();
    asm volatile("s_waitcnt lgkmcnt(0)" ::: "memory");
    __builtin_amdgcn_s_setprio(1);
#pragma unroll
    for (int m = 4; m < 8; ++m)
#pragma unroll
      for (int n = 0; n < 2; ++n) {
        MFMA(acc[m][n], a[m][0], b[n][0]);
        MFMA(acc[m][n], a[m][1], b[n][1]);
      }
    __builtin_amdgcn_s_setprio(0);
    __builtin_amdgcn_s_barrier();

    // ---- p3: read NEXT a0-3 | stage A(t+2)h0+h1 | q3 | tile-end vmcnt ----
    if (t + 1 < NT) {
#pragma unroll
      for (int m = 0; m < 4; ++m) {
        a[m][0] = LDA(ArdN, m, 0); a[m][1] = LDA(ArdN, m, 1);
      }
    }
    if (t + 2 < NT) { STAGE_A(d, t + 2, 0); STAGE_A(d, t + 2, 1); }
    __builtin_amdgcn_s_barrier();
    __builtin_amdgcn_s_setprio(1);
#pragma unroll
    for (int m = 4; m < 8; ++m)
#pragma unroll
      for (int n = 2; n < 4; ++n) {
        MFMA(acc[m][n], a[m][0], b[n][0]);
        MFMA(acc[m][n], a[m][1], b[n][1]);
      }
    __builtin_amdgcn_s_setprio(0);
    if (t < NT - 2) {
      asm volatile("s_waitcnt vmcnt(4)" ::: "memory");  // B(t+1) landed
    } else {
      asm volatile("s_waitcnt vmcnt(0)" ::: "memory");  // tail drain
    }
    __builtin_amdgcn_s_barrier();
  }

  // --- epilogue: per-wave LDS transpose -> coalesced f32x4 stores ----------
  {
    const int wrow0 = row0 + wm * 128;
    const int wcol0 = col0 + wn * 64;
    float* eps = (float*)lds + wave * 2176;  // 32*68 f32, wave-private
    const f32x4 s4 = *(const f32x4*)(scale + wcol0 + 4 * r);
    const f32x4 z4 = *(const f32x4*)(zp + wcol0 + 4 * r);
    const f32x4 b4 = *(const f32x4*)(bias + wcol0 + 4 * r);
    const f32x4 szp4 = s4 * z4;
#pragma unroll
    for (int c = 0; c < 4; ++c) {
#pragma unroll
      for (int mm = 0; mm < 2; ++mm)
#pragma unroll
        for (int n = 0; n < 4; ++n)
#pragma unroll
          for (int q = 0; q < 4; ++q)
            eps[(mm * 16 + g * 4 + q) * 68 + n * 16 + r] =
                acc[2 * c + mm][n][q];
      asm volatile("s_waitcnt lgkmcnt(0)" ::: "memory");
#pragma unroll
      for (int j = 0; j < 8; ++j) {
        const int rl = j * 4 + g;                 // 0..31
        const int grow = wrow0 + c * 32 + rl;
        const f32x4 v = *(const f32x4*)(eps + rl * 68 + 4 * r);
        const float rs = rowsum[grow];
        const f32x4 o4 = s4 * v - szp4 * rs + b4;
        *(f32x4*)(out + (size_t)grow * NDIM + wcol0 + 4 * r) = o4;
      }
      asm volatile("s_waitcnt lgkmcnt(0)" ::: "memory");  // WAR before reuse
    }
  }
#undef STAGE_A
#undef STAGE_B
#undef LDA
#undef LDB
#undef MFMA
}

// --- launch ------------------------------------------------------------------

extern "C" void kernel_launch(void* const* d_in, const int* in_sizes, int n_in,
                              void* d_out, int out_size, void* d_ws,
                              size_t ws_size, hipStream_t stream) {
  const float* x = (const float*)d_in[0];
  const int* wq = (const int*)d_in[1];
  const float* scale = (const float*)d_in[2];
  const float* zp = (const float*)d_in[3];
  const float* bias = (const float*)d_in[4];
  float* out = (float*)d_out;

  char* ws = (char*)d_ws;
  u16* xb = (u16*)ws;                                   // 64 MiB
  u16* wb = (u16*)(ws + (size_t)M_TOK * KDIM * 2);      // 32 MiB
  float* rowsum = (float*)(ws + (size_t)M_TOK * KDIM * 2 +
                           (size_t)NDIM * KDIM * 2);    // 32 KiB

  // 128 KiB dynamic LDS: raise the cap (idempotent, not a stream op)
  hipFuncSetAttribute((const void*)qlin_gemm_kernel,
                      hipFuncAttributeMaxDynamicSharedMemorySize, 131072);

  convert_x_kernel<<<M_TOK, 256, 0, stream>>>(x, xb, rowsum);
  convert_w_kernel<<<(NDIM * (size_t)KDIM) / (256 * 8), 256, 0, stream>>>(wq, wb);

  qlin_gemm_kernel<<<dim3((M_TOK / 256) * (NDIM / 256)), dim3(512), 131072,
                     stream>>>(xb, wb, rowsum, scale, zp, bias, out);
}

// Round 7
// 178.925 us; speedup vs baseline: 1.8870x; 1.5507x over previous
//
#include <hip/hip_runtime.h>

// ---------------------------------------------------------------------------
// QuantizedLinear: y = x @ ((q - zp)*s)^T + bias    — INT8 MFMA path.
// Per-row x quant: s_x[m] = max|x[m,:]|/127, xq = rint(x/s_x)  (s8)
// Weight: qs8 = q - 128 (exact).  Then, EXACTLY:
//   y[m,o] = s_x[m]*s[o]*( G8[m,o] + (128-zp[o])*rq[m] ) + bias[o]
//   G8 = Xq @ Qs8^T (i32, exact), rq[m] = sum_k xq[m,k] (i32, exact).
// Only error source: x quantization (est absmax ~1 << 18.64 threshold).
// GEMM: same verified 256x256 4-phase pipelined structure as round 5
// (all byte-level addressing identical: 128-B K-tile rows, slot^(row&7)
// swizzle, counted vmcnt 4/0, T5 setprio, T1 XCD swizzle), with
// mfma_i32_16x16x64_i8 (same 4-reg A/B/C geometry as 16x16x32_bf16).
// NT = 32 (K=4096 / 128 i8 per tile).
// ---------------------------------------------------------------------------

typedef unsigned char u8;
typedef signed char s8;
typedef __attribute__((ext_vector_type(4))) int i32x4;
typedef __attribute__((ext_vector_type(4))) float f32x4;

#define M_TOK 8192
#define KDIM 4096   // K elements == K bytes (i8)
#define NDIM 4096
#define NT (KDIM / 128)  // 32 K-tiles of 128 i8

// --- helpers ---------------------------------------------------------------

__device__ __forceinline__ int pack4(int a, int b, int c, int d) {
  return (a & 255) | ((b & 255) << 8) | ((c & 255) << 16) |
         (int)(((unsigned)(d & 255)) << 24);
}

#define GLDS(gptr, lptr)                                                      \
  __builtin_amdgcn_global_load_lds(                                          \
      (const __attribute__((address_space(1))) void*)(gptr),                 \
      (__attribute__((address_space(3))) void*)(lptr), 16, 0, 0)

// --- kernel 1: x f32 -> s8 per-row quant, fused row max + row sum ----------

__global__ __launch_bounds__(256) void convert_x_kernel(
    const float* __restrict__ x, s8* __restrict__ xq,
    float* __restrict__ sx, float* __restrict__ rq) {
  const int row = blockIdx.x;
  const int tid = threadIdx.x;
  const float* xr = x + (size_t)row * KDIM + tid * 16;
  float4 v[4];
#pragma unroll
  for (int i = 0; i < 4; ++i) v[i] = ((const float4*)xr)[i];

  float mx = 0.f;
#pragma unroll
  for (int i = 0; i < 4; ++i) {
    mx = fmaxf(mx, fabsf(v[i].x)); mx = fmaxf(mx, fabsf(v[i].y));
    mx = fmaxf(mx, fabsf(v[i].z)); mx = fmaxf(mx, fabsf(v[i].w));
  }
#pragma unroll
  for (int off = 32; off > 0; off >>= 1)
    mx = fmaxf(mx, __shfl_down(mx, off, 64));
  __shared__ float redf[4];
  __shared__ float bmax;
  if ((tid & 63) == 0) redf[tid >> 6] = mx;
  __syncthreads();
  if (tid == 0)
    bmax = fmaxf(fmaxf(redf[0], redf[1]), fmaxf(redf[2], redf[3]));
  __syncthreads();
  const float maxv = bmax;
  const float inv = 127.0f / fmaxf(maxv, 1e-30f);

  int q[16];
  int ssum = 0;
#pragma unroll
  for (int i = 0; i < 4; ++i) {
    q[i * 4 + 0] = (int)rintf(v[i].x * inv);
    q[i * 4 + 1] = (int)rintf(v[i].y * inv);
    q[i * 4 + 2] = (int)rintf(v[i].z * inv);
    q[i * 4 + 3] = (int)rintf(v[i].w * inv);
  }
#pragma unroll
  for (int i = 0; i < 16; ++i) ssum += q[i];

  int4 o;
  o.x = pack4(q[0], q[1], q[2], q[3]);
  o.y = pack4(q[4], q[5], q[6], q[7]);
  o.z = pack4(q[8], q[9], q[10], q[11]);
  o.w = pack4(q[12], q[13], q[14], q[15]);
  *(int4*)(xq + (size_t)row * KDIM + tid * 16) = o;

#pragma unroll
  for (int off = 32; off > 0; off >>= 1) ssum += __shfl_down(ssum, off, 64);
  __shared__ int redi[4];
  if ((tid & 63) == 0) redi[tid >> 6] = ssum;
  __syncthreads();
  if (tid == 0) {
    sx[row] = maxv * (1.0f / 127.0f);
    rq[row] = (float)(redi[0] + redi[1] + redi[2] + redi[3]);  // < 2^24 exact
  }
}

// --- kernel 2: w int32 -> s8 (q - 128, exact) --------------------------------

__global__ __launch_bounds__(256) void convert_w_kernel(
    const int* __restrict__ wq, s8* __restrict__ wb) {
  const size_t idx = (size_t)blockIdx.x * 256 + threadIdx.x;  // 16 elems each
  const int4* src = (const int4*)wq + idx * 4;
  const int4 a = src[0], b = src[1], c = src[2], d = src[3];
  int4 o;
  o.x = pack4(a.x - 128, a.y - 128, a.z - 128, a.w - 128);
  o.y = pack4(b.x - 128, b.y - 128, b.z - 128, b.w - 128);
  o.z = pack4(c.x - 128, c.y - 128, c.z - 128, c.w - 128);
  o.w = pack4(d.x - 128, d.y - 128, d.z - 128, d.w - 128);
  ((int4*)wb)[idx] = o;
}

// --- kernel 3: 256x256 pipelined i8 GEMM, fused dequant epilogue ------------
// LDS: Al[2][256][128B], Bl[2][256][128B] = 128 KiB (dynamic). Byte layout
// IDENTICAL to the bf16 version (128-B rows, 16-B slots, slot^(row&7)).
// Phases p0..p3 per K-tile, stage schedule and vmcnt/lgkm ledger identical
// to round 5 (verified): p0 B(t+1)h0, p1 B(t+1)h1, p3 A(t+2)h0+h1;
// p2 vmcnt(4); tile-end vmcnt(4) steady / vmcnt(0) last two tiles.

__global__ __launch_bounds__(512, 2) void qlin_gemm_kernel(
    const u8* __restrict__ A,         // [M][K] s8 bits
    const u8* __restrict__ B,         // [N][K] s8 bits
    const float* __restrict__ sx,     // [M] x row scale
    const float* __restrict__ rq,     // [M] x row qsum (as float)
    const float* __restrict__ scale,  // [N]
    const float* __restrict__ zp,     // [N]
    const float* __restrict__ bias,   // [N]
    float* __restrict__ out) {        // [M][N]
  extern __shared__ u8 lds[];
  u8* Al = lds;           // [2][256][128]
  u8* Bl = lds + 65536;   // [2][256][128]

  const int tid = threadIdx.x;
  const int lane = tid & 63;
  const int wave = tid >> 6;
  const int wm = wave >> 2;  // 0..1
  const int wn = wave & 3;   // 0..3

  // T1: bijective XCD swizzle (512 wgs, 512%8==0)
  const int bid = blockIdx.x;
  const int swz = (bid & 7) * 64 + (bid >> 3);
  const int bm = swz >> 4;   // 0..31
  const int bn = swz & 15;   // 0..15
  const int row0 = bm * 256, col0 = bn * 256;

  // staging: thread t -> row t>>3, slot (t&7)^(row&7) pre-swizzled source.
  // LDS dest WAVE-UNIFORM; HW writes lane i at base + i*16 (m104).
  const int sr = tid >> 3;
  const int ss = (tid & 7) ^ (sr & 7);
  const u8* Ags = A + (size_t)(row0 + sr) * KDIM + ss * 16;
  const u8* Bgs = B + (size_t)(col0 + sr) * KDIM + ss * 16;
  u8* Ald = Al + wave * 1024;
  u8* Bld = Bl + wave * 1024;

#define STAGE_A(d, tau, h)                                                    \
  do {                                                                        \
    const u8* _g = Ags + (size_t)(h) * 128 * KDIM + (tau) * 128;             \
    u8* _l = Ald + (d) * 32768 + (h) * 16384;                                \
    GLDS(_g, _l);                                                            \
    GLDS(_g + (size_t)64 * KDIM, _l + 8192);                                 \
  } while (0)

#define STAGE_B(d, tau, h)                                                    \
  do {                                                                        \
    const u8* _g = Bgs + (size_t)(h) * 128 * KDIM + (tau) * 128;             \
    u8* _l = Bld + (d) * 32768 + (h) * 16384;                                \
    GLDS(_g, _l);                                                            \
    GLDS(_g + (size_t)64 * KDIM, _l + 8192);                                 \
  } while (0)

  // fragment reads: lane (g=lane>>4, r=lane&15) reads row <dim0>+r,
  // byte col (ks*64 + g*16) ^ ((r&7)<<4).  16x16x64_i8: lane holds k =
  // g*16..g*16+15 (16 B contiguous), same slot geometry as bf16 16x16x32.
  const int r = lane & 15;
  const int g = lane >> 4;
  const int swzx = (lane & 7) << 4;
  const int ce0 = (g * 16) ^ swzx;        // bytes, ks=0
  const int ce1 = (64 + g * 16) ^ swzx;   // bytes, ks=1
  const u8* Ar = Al + (wm * 128 + r) * 128;
  const u8* Br = Bl + (wn * 64 + r) * 128;

#define LDA(base, m, ks) \
  (*(const i32x4*)((base) + (m) * 2048 + ((ks) ? ce1 : ce0)))
#define LDB(base, n, ks) \
  (*(const i32x4*)((base) + (n) * 2048 + ((ks) ? ce1 : ce0)))
#define MFMA(d, va, vb) \
  d = __builtin_amdgcn_mfma_i32_16x16x64_i8(va, vb, d, 0, 0, 0)

  i32x4 acc[8][4] = {};
  i32x4 a[8][2], b[4][2];

  // prologue: A(0), B(0), A(1); vmcnt(4) -> tile0 landed, A(1) in flight;
  // prefetch a0-3 of tile 0.
  STAGE_A(0, 0, 0); STAGE_A(0, 0, 1);
  STAGE_B(0, 0, 0); STAGE_B(0, 0, 1);
  STAGE_A(1, 1, 0); STAGE_A(1, 1, 1);
  asm volatile("s_waitcnt vmcnt(4)" ::: "memory");
  __builtin_amdgcn_s_barrier();
#pragma unroll
  for (int m = 0; m < 4; ++m) {
    a[m][0] = LDA(Ar, m, 0); a[m][1] = LDA(Ar, m, 1);
  }

  for (int t = 0; t < NT; ++t) {
    const int d = t & 1;
    const u8* Ard = Ar + d * 32768;
    const u8* Brd = Br + d * 32768;
    const u8* ArdN = Ar + (d ^ 1) * 32768;

    // ---- p0: read b0-1 | fence | b2-3 | stage B(t+1)h0 | lgkm(4) | q0 ----
#pragma unroll
    for (int n = 0; n < 2; ++n) {
      b[n][0] = LDB(Brd, n, 0); b[n][1] = LDB(Brd, n, 1);
    }
    asm volatile("" ::: "memory");  // pin b0-1 before b2-3 (counted lgkm)
#pragma unroll
    for (int n = 2; n < 4; ++n) {
      b[n][0] = LDB(Brd, n, 0); b[n][1] = LDB(Brd, n, 1);
    }
    if (t + 1 < NT) STAGE_B(d ^ 1, t + 1, 0);
    __builtin_amdgcn_s_barrier();
    asm volatile("s_waitcnt lgkmcnt(4)" ::: "memory");  // a0-3,b0-1 ready
    __builtin_amdgcn_s_setprio(1);
#pragma unroll
    for (int m = 0; m < 4; ++m)
#pragma unroll
      for (int n = 0; n < 2; ++n) {
        MFMA(acc[m][n], a[m][0], b[n][0]);
        MFMA(acc[m][n], a[m][1], b[n][1]);
      }
    __builtin_amdgcn_s_setprio(0);
    __builtin_amdgcn_s_barrier();

    // ---- p1: read a4-7 | stage B(t+1)h1 | lgkm(8) | q1 ----
#pragma unroll
    for (int m = 4; m < 8; ++m) {
      a[m][0] = LDA(Ard, m, 0); a[m][1] = LDA(Ard, m, 1);
    }
    if (t + 1 < NT) STAGE_B(d ^ 1, t + 1, 1);
    __builtin_amdgcn_s_barrier();
    asm volatile("s_waitcnt lgkmcnt(8)" ::: "memory");  // b2-3 ready
    __builtin_amdgcn_s_setprio(1);
#pragma unroll
    for (int m = 0; m < 4; ++m)
#pragma unroll
      for (int n = 2; n < 4; ++n) {
        MFMA(acc[m][n], a[m][0], b[n][0]);
        MFMA(acc[m][n], a[m][1], b[n][1]);
      }
    __builtin_amdgcn_s_setprio(0);
    __builtin_amdgcn_s_barrier();

    // ---- p2: vmcnt(4): A(t+1) landed | lgkm(0): a4-7 ready | q2 ----
    if (t + 1 < NT) {
      asm volatile("s_waitcnt vmcnt(4)" ::: "memory");
    }
    __builtin_amdgcn_s_barrier();
    asm volatile("s_waitcnt lgkmcnt(0)" ::: "memory");
    __builtin_amdgcn_s_setprio(1);
#pragma unroll
    for (int m = 4; m < 8; ++m)
#pragma unroll
      for (int n = 0; n < 2; ++n) {
        MFMA(acc[m][n], a[m][0], b[n][0]);
        MFMA(acc[m][n], a[m][1], b[n][1]);
      }
    __builtin_amdgcn_s_setprio(0);
    __builtin_amdgcn_s_barrier();

    // ---- p3: read NEXT a0-3 | stage A(t+2)h0+h1 | q3 | tile-end vmcnt ----
    if (t + 1 < NT) {
#pragma unroll
      for (int m = 0; m < 4; ++m) {
        a[m][0] = LDA(ArdN, m, 0); a[m][1] = LDA(ArdN, m, 1);
      }
    }
    if (t + 2 < NT) { STAGE_A(d, t + 2, 0); STAGE_A(d, t + 2, 1); }
    __builtin_amdgcn_s_barrier();
    __builtin_amdgcn_s_setprio(1);
#pragma unroll
    for (int m = 4; m < 8; ++m)
#pragma unroll
      for (int n = 2; n < 4; ++n) {
        MFMA(acc[m][n], a[m][0], b[n][0]);
        MFMA(acc[m][n], a[m][1], b[n][1]);
      }
    __builtin_amdgcn_s_setprio(0);
    if (t < NT - 2) {
      asm volatile("s_waitcnt vmcnt(4)" ::: "memory");  // B(t+1) landed
    } else {
      asm volatile("s_waitcnt vmcnt(0)" ::: "memory");  // tail drain
    }
    __builtin_amdgcn_s_barrier();
  }

  // --- epilogue: i32->f32, per-wave LDS transpose, coalesced f32x4 stores ---
  // y = sx[row]*( s[col]*G + s[col]*(128-zp[col])*rq[row] ) + bias[col]
  {
    const int wrow0 = row0 + wm * 128;
    const int wcol0 = col0 + wn * 64;
    float* eps = (float*)lds + wave * 2176;  // 32x68 f32, wave-private
    const f32x4 p4 = *(const f32x4*)(scale + wcol0 + 4 * r);
    const f32x4 z4 = *(const f32x4*)(zp + wcol0 + 4 * r);
    const f32x4 b4 = *(const f32x4*)(bias + wcol0 + 4 * r);
    const f32x4 w04 = p4 * (128.0f - z4);
#pragma unroll
    for (int c = 0; c < 4; ++c) {
#pragma unroll
      for (int mm = 0; mm < 2; ++mm)
#pragma unroll
        for (int n = 0; n < 4; ++n)
#pragma unroll
          for (int q = 0; q < 4; ++q)
            eps[(mm * 16 + g * 4 + q) * 68 + n * 16 + r] =
                (float)acc[2 * c + mm][n][q];
      asm volatile("s_waitcnt lgkmcnt(0)" ::: "memory");
#pragma unroll
      for (int j = 0; j < 8; ++j) {
        const int rl = j * 4 + g;                 // 0..31
        const int grow = wrow0 + c * 32 + rl;
        const f32x4 v = *(const f32x4*)(eps + rl * 68 + 4 * r);
        const float sxr = sx[grow];
        const float rqr = rq[grow];
        const f32x4 o4 = sxr * (p4 * v + w04 * rqr) + b4;
        *(f32x4*)(out + (size_t)grow * NDIM + wcol0 + 4 * r) = o4;
      }
      asm volatile("s_waitcnt lgkmcnt(0)" ::: "memory");  // WAR before reuse
    }
  }
#undef STAGE_A
#undef STAGE_B
#undef LDA
#undef LDB
#undef MFMA
}

// --- launch ------------------------------------------------------------------

extern "C" void kernel_launch(void* const* d_in, const int* in_sizes, int n_in,
                              void* d_out, int out_size, void* d_ws,
                              size_t ws_size, hipStream_t stream) {
  const float* x = (const float*)d_in[0];
  const int* wq = (const int*)d_in[1];
  const float* scale = (const float*)d_in[2];
  const float* zp = (const float*)d_in[3];
  const float* bias = (const float*)d_in[4];
  float* out = (float*)d_out;

  // workspace: xq 32 MiB | wq8 16 MiB | sx 32 KiB | rq 32 KiB  (~48.1 MiB)
  char* ws = (char*)d_ws;
  s8* xq = (s8*)ws;
  s8* wq8 = (s8*)(ws + (size_t)M_TOK * KDIM);
  float* sx = (float*)(ws + (size_t)M_TOK * KDIM + (size_t)NDIM * KDIM);
  float* rq = (float*)(ws + (size_t)M_TOK * KDIM + (size_t)NDIM * KDIM +
                       (size_t)M_TOK * 4);

  (void)hipFuncSetAttribute((const void*)qlin_gemm_kernel,
                            hipFuncAttributeMaxDynamicSharedMemorySize,
                            131072);

  convert_x_kernel<<<M_TOK, 256, 0, stream>>>(x, xq, sx, rq);
  convert_w_kernel<<<(NDIM * (size_t)KDIM) / (256 * 16), 256, 0, stream>>>(
      wq, wq8);

  qlin_gemm_kernel<<<dim3((M_TOK / 256) * (NDIM / 256)), dim3(512), 131072,
                     stream>>>((const u8*)xq, (const u8*)wq8, sx, rq, scale,
                               zp, bias, out);
}